// Round 1
// baseline (1428.402 us; speedup 1.0000x reference)
//
#include <hip/hip_runtime.h>
#include <hip/hip_bf16.h>
#include <cstdint>
#include <cstddef>

// Problem constants
#define B_   2
#define C_   256
#define NSP  110592      // 48*48*48
#define NH_  4
#define DQK  32
#define DV   64
#define EPS_ 1e-6f

typedef unsigned short ushort_t;
typedef unsigned int   uint_t;

__device__ __forceinline__ float bf2f(ushort_t h) {
    union { uint32_t u; float f; } v;
    v.u = ((uint32_t)h) << 16;
    return v.f;
}
__device__ __forceinline__ ushort_t f2bf(float f) {
    union { float f; uint32_t u; } v;
    v.f = f;
    uint32_t u = v.u;
    uint32_t r = u + 0x7FFFu + ((u >> 16) & 1u);   // RNE
    return (ushort_t)(r >> 16);
}

// ---------------------------------------------------------------------------
// K1: qk GEMM.  qk[b][o][n] = sum_c W[o][c] * x[b][c][n]
//  o in [0,128): Wq rows (q);  o in [128,256): Wk rows (k).  Stored bf16.
//  grid (864, 2, 2) = (n-tiles of 128, o-tile, b); block 256.
// ---------------------------------------------------------------------------
__global__ __launch_bounds__(256) void k1_gemm(
    const float* __restrict__ x, const float* __restrict__ Wq,
    const float* __restrict__ Wk, ushort_t* __restrict__ qk)
{
    __shared__ float Xs[16][128];
    __shared__ float Ws[16][132];
    const int t  = threadIdx.x;
    const int tx = t & 15, ty = t >> 4;
    const int nb = blockIdx.x, ob = blockIdx.y, b = blockIdx.z;
    const float* Wsel = ob ? Wk : Wq;
    const float* xb = x + (size_t)b * C_ * (size_t)NSP + (size_t)nb * 128;

    float acc[8][8];
#pragma unroll
    for (int i = 0; i < 8; i++)
#pragma unroll
        for (int j = 0; j < 8; j++) acc[i][j] = 0.f;

    for (int c0 = 0; c0 < 256; c0 += 16) {
        // stage X tile [16 c][128 n]
#pragma unroll
        for (int i = 0; i < 2; i++) {
            int idx = t + i * 256;
            int r = idx >> 5, col = (idx & 31) << 2;
            *(float4*)&Xs[r][col] =
                *(const float4*)(xb + (size_t)(c0 + r) * NSP + col);
        }
        // stage W tile transposed: Ws[kc][o]
#pragma unroll
        for (int i = 0; i < 2; i++) {
            int idx = t + i * 256;
            int o = idx >> 2, c4 = (idx & 3) << 2;
            float4 w = *(const float4*)(Wsel + o * 256 + c0 + c4);
            Ws[c4 + 0][o] = w.x; Ws[c4 + 1][o] = w.y;
            Ws[c4 + 2][o] = w.z; Ws[c4 + 3][o] = w.w;
        }
        __syncthreads();
#pragma unroll
        for (int kc = 0; kc < 16; kc++) {
            float4 x0 = *(const float4*)&Xs[kc][tx * 8];
            float4 x1 = *(const float4*)&Xs[kc][tx * 8 + 4];
            float4 w0 = *(const float4*)&Ws[kc][ty * 8];
            float4 w1 = *(const float4*)&Ws[kc][ty * 8 + 4];
            float xr[8] = {x0.x, x0.y, x0.z, x0.w, x1.x, x1.y, x1.z, x1.w};
            float wr[8] = {w0.x, w0.y, w0.z, w0.w, w1.x, w1.y, w1.z, w1.w};
#pragma unroll
            for (int i = 0; i < 8; i++)
#pragma unroll
                for (int j = 0; j < 8; j++)
                    acc[i][j] += wr[i] * xr[j];
        }
        __syncthreads();
    }

    size_t obase = ((size_t)(b * 256 + ob * 128 + ty * 8)) * NSP
                 + (size_t)nb * 128 + tx * 8;
#pragma unroll
    for (int i = 0; i < 8; i++) {
        ushort_t u[8];
#pragma unroll
        for (int j = 0; j < 8; j++) u[j] = f2bf(acc[i][j]);
        uint4 pk;
        pk.x = (uint_t)u[0] | ((uint_t)u[1] << 16);
        pk.y = (uint_t)u[2] | ((uint_t)u[3] << 16);
        pk.z = (uint_t)u[4] | ((uint_t)u[5] << 16);
        pk.w = (uint_t)u[6] | ((uint_t)u[7] << 16);
        *(uint4*)(qk + obase + (size_t)i * NSP) = pk;
    }
}

// ---------------------------------------------------------------------------
// K2: depthwise 3x3x3 conv + bias -> v (bf16), v stored into d_out scratch.
//  grid (108, 512=b*256+c); block 256.  4 outputs along d per thread.
// ---------------------------------------------------------------------------
__global__ __launch_bounds__(256) void k2_conv(
    const float* __restrict__ x, const float* __restrict__ Wv,
    const float* __restrict__ bv, ushort_t* __restrict__ v)
{
    const int gy = blockIdx.y;
    const int b = gy >> 8, c = gy & 255;
    const int qid = blockIdx.x * 256 + threadIdx.x;  // < 27648
    const int dd0  = (qid % 12) * 4;
    const int rest = qid / 12;                        // hh*48+ww
    const int ww = rest % 48, hh = rest / 48;

    float wv[27];
    {
        const float* w = Wv + c * 27;
#pragma unroll
        for (int i = 0; i < 27; i++) wv[i] = w[i];
    }
    const float bias = bv[c];
    const float* xb = x + ((size_t)(b * 256 + c)) * NSP;

    float a0 = bias, a1 = bias, a2 = bias, a3 = bias;
#pragma unroll
    for (int dh = 0; dh < 3; dh++) {
        int ih = hh + dh - 1;
        if (ih < 0 || ih >= 48) continue;
#pragma unroll
        for (int dw = 0; dw < 3; dw++) {
            int iw = ww + dw - 1;
            if (iw < 0 || iw >= 48) continue;
            const float* row = xb + ((size_t)(ih * 48 + iw)) * 48;
            float4 m  = *(const float4*)(row + dd0);
            float  lm = (dd0 > 0)  ? row[dd0 - 1] : 0.f;
            float  rp = (dd0 < 44) ? row[dd0 + 4] : 0.f;
            const int wb = (dh * 3 + dw) * 3;
            float w0 = wv[wb], w1 = wv[wb + 1], w2 = wv[wb + 2];
            a0 += w0 * lm  + w1 * m.x + w2 * m.y;
            a1 += w0 * m.x + w1 * m.y + w2 * m.z;
            a2 += w0 * m.y + w1 * m.z + w2 * m.w;
            a3 += w0 * m.z + w1 * m.w + w2 * rp;
        }
    }
    ushort4 o;
    o.x = f2bf(a0); o.y = f2bf(a1); o.z = f2bf(a2); o.w = f2bf(a3);
    *(ushort4*)(v + (size_t)gy * NSP + (size_t)rest * 48 + dd0) = o;
}

// ---------------------------------------------------------------------------
// K3: KVu[bh][kq][cv] += sum_n exp(k[kq][n]) * v[cv][n]
//  grid (108 pos-blocks of 1024, 8 = b*4+h); block 256 (4 waves).
//  LDS chunk = 256 positions; thread owns 4kq x 8cv accumulators.
// ---------------------------------------------------------------------------
__global__ __launch_bounds__(256) void k3_kv(
    const ushort_t* __restrict__ qk, const ushort_t* __restrict__ v,
    float* __restrict__ KVu)
{
    __shared__ __align__(16) char smem[49920];
    ushort_t* ks = (ushort_t*)smem;                 // [32][260] bf16
    ushort_t* vs = (ushort_t*)(smem + 16640);       // [64][260] bf16
    const int S = 260;

    const int bh = blockIdx.y;
    const int b = bh >> 2, h = bh & 3;
    const int t = threadIdx.x;
    const int lane = t & 63, w = t >> 6;
    const int kq0 = (lane >> 3) * 4;
    const int cv0 = (lane & 7) * 8;

    const ushort_t* kbase0 = qk + ((size_t)(b * 256 + 128 + h * 32)) * NSP;
    const ushort_t* vbase0 = v  + ((size_t)(b * 256 + h * 64)) * NSP;

    float acc[4][8];
#pragma unroll
    for (int r = 0; r < 4; r++)
#pragma unroll
        for (int u = 0; u < 8; u++) acc[r][u] = 0.f;

    for (int ch = 0; ch < 4; ch++) {
        const int pos = blockIdx.x * 1024 + ch * 256;
        // stage k (with exp) : 32 rows x 256
#pragma unroll
        for (int i = 0; i < 4; i++) {
            int g = t + i * 256;
            int r = g >> 5, seg = (g & 31) * 8;
            uint4 raw = *(const uint4*)(kbase0 + (size_t)r * NSP + pos + seg);
            const ushort_t* in = (const ushort_t*)&raw;
            union { ushort_t s[8]; uint2 d[2]; } tmp;
#pragma unroll
            for (int e = 0; e < 8; e++) tmp.s[e] = f2bf(__expf(bf2f(in[e])));
            ushort_t* dst = ks + r * S + seg;
            *(uint2*)dst       = tmp.d[0];
            *(uint2*)(dst + 4) = tmp.d[1];
        }
        // stage v : 64 rows x 256 (copy)
#pragma unroll
        for (int i = 0; i < 8; i++) {
            int g = t + i * 256;
            int r = g >> 5, seg = (g & 31) * 8;
            uint4 raw = *(const uint4*)(vbase0 + (size_t)r * NSP + pos + seg);
            ushort_t* dst = vs + r * S + seg;
            *(uint2*)dst       = make_uint2(raw.x, raw.y);
            *(uint2*)(dst + 4) = make_uint2(raw.z, raw.w);
        }
        __syncthreads();
        // compute: wave w covers positions [w*64, w*64+64)
#pragma unroll 4
        for (int i = 0; i < 16; i++) {
            int p = w * 64 + i * 4;
            float kf[4][4];
#pragma unroll
            for (int r = 0; r < 4; r++) {
                uint2 kr = *(const uint2*)(ks + (kq0 + r) * S + p);
                const ushort_t* u = (const ushort_t*)&kr;
                kf[r][0] = bf2f(u[0]); kf[r][1] = bf2f(u[1]);
                kf[r][2] = bf2f(u[2]); kf[r][3] = bf2f(u[3]);
            }
#pragma unroll
            for (int uu = 0; uu < 8; uu++) {
                uint2 vr = *(const uint2*)(vs + (cv0 + uu) * S + p);
                const ushort_t* u = (const ushort_t*)&vr;
                float vf0 = bf2f(u[0]), vf1 = bf2f(u[1]);
                float vf2 = bf2f(u[2]), vf3 = bf2f(u[3]);
#pragma unroll
                for (int r = 0; r < 4; r++) {
                    acc[r][uu] += kf[r][0] * vf0 + kf[r][1] * vf1
                                + kf[r][2] * vf2 + kf[r][3] * vf3;
                }
            }
        }
        __syncthreads();
    }

    // block reduction across 4 waves, then global atomics
    float* red = (float*)smem;   // 4*2048 floats = 32KB (aliases ks/vs, all done)
#pragma unroll
    for (int r = 0; r < 4; r++)
#pragma unroll
        for (int u = 0; u < 8; u++)
            red[w * 2048 + (kq0 + r) * 64 + cv0 + u] = acc[r][u];
    __syncthreads();
    float* KVb = KVu + (size_t)bh * 2048;
    for (int e = t; e < 2048; e += 256) {
        float s = red[e] + red[e + 2048] + red[e + 4096] + red[e + 6144];
        atomicAdd(KVb + e, s);
    }
}

// ---------------------------------------------------------------------------
// K3b: SE[b*128+row] = sum_n exp(k[row][n]).  grid 256 blocks; block 256.
// ---------------------------------------------------------------------------
__global__ __launch_bounds__(256) void k3b_se(
    const ushort_t* __restrict__ qk, float* __restrict__ SE)
{
    const int row = blockIdx.x & 127, b = blockIdx.x >> 7;
    const ushort_t* kr = qk + ((size_t)(b * 256 + 128 + row)) * NSP;
    float s = 0.f;
    for (int i = threadIdx.x; i < NSP / 8; i += 256) {
        uint4 u4 = *(const uint4*)(kr + (size_t)i * 8);
        const ushort_t* us = (const ushort_t*)&u4;
#pragma unroll
        for (int e = 0; e < 8; e++) s += __expf(bf2f(us[e]));
    }
#pragma unroll
    for (int off = 32; off > 0; off >>= 1) s += __shfl_down(s, off, 64);
    __shared__ float partial[4];
    if ((threadIdx.x & 63) == 0) partial[threadIdx.x >> 6] = s;
    __syncthreads();
    if (threadIdx.x == 0)
        SE[blockIdx.x] = partial[0] + partial[1] + partial[2] + partial[3];
}

// ---------------------------------------------------------------------------
// K4: out[b][h*64+cv][n] = sum_kq softmax_kq(q)[kq][n] * KVu[kq][cv]/SE[kq]
//                          / (1+EPS)
//  grid (432 chunks of 256 pos, 8 = b*4+h); block 256.
// ---------------------------------------------------------------------------
__global__ __launch_bounds__(256) void k4_fin(
    const ushort_t* __restrict__ qk, const float* __restrict__ KVu,
    const float* __restrict__ SE, float* __restrict__ out)
{
    __shared__ float qsf[32 * 260];
    __shared__ float KVs[2048];
    const int bh = blockIdx.y;
    const int b = bh >> 2, h = bh & 3;
    const int pos0 = blockIdx.x * 256;
    const int t = threadIdx.x;

    // KV with SE + (1+eps) folded in
    {
        const float* src = KVu + (size_t)bh * 2048;
        const float* se  = SE + b * 128 + h * 32;
        int kq = t >> 3;
        float inv = 1.0f / (se[kq] * (1.0f + EPS_));
        float4 a = *(const float4*)(src + t * 8);
        float4 c = *(const float4*)(src + t * 8 + 4);
        a.x *= inv; a.y *= inv; a.z *= inv; a.w *= inv;
        c.x *= inv; c.y *= inv; c.z *= inv; c.w *= inv;
        *(float4*)(KVs + t * 8)     = a;
        *(float4*)(KVs + t * 8 + 4) = c;
    }
    // phase A: per-position q softmax over 32 features
    {
        const int p = pos0 + t;
        const ushort_t* qb = qk + ((size_t)(b * 256 + h * 32)) * NSP + p;
        float e[32];
        float s = 0.f;
#pragma unroll
        for (int r = 0; r < 32; r++) {
            e[r] = __expf(bf2f(qb[(size_t)r * NSP]));
            s += e[r];
        }
        float inv = 1.0f / s;
#pragma unroll
        for (int r = 0; r < 32; r++) qsf[r * 260 + t] = e[r] * inv;
    }
    __syncthreads();

    // phase B: num = q_s^T * KV  -> out
    const int cv0 = (t & 7) * 8;
    const int pq  = t >> 3;   // 0..31
#pragma unroll
    for (int qd = 0; qd < 2; qd++) {
        const int p0 = pq * 8 + qd * 4;
        float acc[8][4];
#pragma unroll
        for (int u = 0; u < 8; u++)
#pragma unroll
            for (int e = 0; e < 4; e++) acc[u][e] = 0.f;
#pragma unroll
        for (int kq = 0; kq < 32; kq++) {
            float4 qv = *(const float4*)&qsf[kq * 260 + p0];
            float4 k0 = *(const float4*)&KVs[kq * 64 + cv0];
            float4 k1 = *(const float4*)&KVs[kq * 64 + cv0 + 4];
            float kk[8] = {k0.x, k0.y, k0.z, k0.w, k1.x, k1.y, k1.z, k1.w};
#pragma unroll
            for (int u = 0; u < 8; u++) {
                acc[u][0] += kk[u] * qv.x;
                acc[u][1] += kk[u] * qv.y;
                acc[u][2] += kk[u] * qv.z;
                acc[u][3] += kk[u] * qv.w;
            }
        }
        float* ob = out + ((size_t)(b * 256 + h * 64)) * NSP + pos0 + p0;
#pragma unroll
        for (int u = 0; u < 8; u++) {
            *(float4*)(ob + (size_t)(cv0 + u) * NSP) =
                make_float4(acc[u][0], acc[u][1], acc[u][2], acc[u][3]);
        }
    }
}

// ---------------------------------------------------------------------------
extern "C" void kernel_launch(void* const* d_in, const int* in_sizes, int n_in,
                              void* d_out, int out_size, void* d_ws,
                              size_t ws_size, hipStream_t stream)
{
    const float* x  = (const float*)d_in[0];
    const float* Wq = (const float*)d_in[1];
    const float* Wk = (const float*)d_in[2];
    const float* Wv = (const float*)d_in[3];
    const float* bv = (const float*)d_in[4];
    float* out = (float*)d_out;

    // ws layout: qk bf16 [2][256][NSP] (113,246,208 B) | KVu f32 (65,536 B) | SE f32 (1,024 B)
    ushort_t* qk  = (ushort_t*)d_ws;
    float*    KVu = (float*)((char*)d_ws + 113246208);
    float*    SE  = (float*)((char*)d_ws + 113246208 + 65536);
    // v (bf16) scratch lives in the first half of d_out; K4 overwrites later.
    ushort_t* v = (ushort_t*)d_out;

    hipMemsetAsync(KVu, 0, 65536 + 1024, stream);

    k1_gemm<<<dim3(864, 2, 2), 256, 0, stream>>>(x, Wq, Wk, qk);
    k2_conv<<<dim3(108, 512), 256, 0, stream>>>(x, Wv, bv, v);
    k3_kv  <<<dim3(108, 8),   256, 0, stream>>>(qk, v, KVu);
    k3b_se <<<dim3(256),      256, 0, stream>>>(qk, SE);
    k4_fin <<<dim3(432, 8),   256, 0, stream>>>(qk, KVu, SE, out);
}

// Round 2
// 1037.170 us; speedup vs baseline: 1.3772x; 1.3772x over previous
//
#include <hip/hip_runtime.h>
#include <hip/hip_bf16.h>
#include <cstdint>
#include <cstddef>

// Problem constants
#define B_   2
#define C_   256
#define NSP  110592      // 48*48*48
#define NH_  4
#define DQK  32
#define DV   64
#define EPS_ 1e-6f

typedef unsigned short ushort_t;
typedef unsigned int   uint_t;

__device__ __forceinline__ float bf2f(ushort_t h) {
    union { uint32_t u; float f; } v;
    v.u = ((uint32_t)h) << 16;
    return v.f;
}
__device__ __forceinline__ ushort_t f2bf(float f) {
    union { float f; uint32_t u; } v;
    v.f = f;
    uint32_t u = v.u;
    uint32_t r = u + 0x7FFFu + ((u >> 16) & 1u);   // RNE
    return (ushort_t)(r >> 16);
}

// ---------------------------------------------------------------------------
// K1: qk GEMM.  qk[b][o][n] = sum_c W[o][c] * x[b][c][n]
//  o in [0,128): Wq rows (q);  o in [128,256): Wk rows (k).  Stored bf16.
//  grid (864, 2, 2) = (n-tiles of 128, o-tile, b); block 256.
// ---------------------------------------------------------------------------
__global__ __launch_bounds__(256) void k1_gemm(
    const float* __restrict__ x, const float* __restrict__ Wq,
    const float* __restrict__ Wk, ushort_t* __restrict__ qk)
{
    __shared__ float Xs[16][128];
    __shared__ float Ws[16][132];
    const int t  = threadIdx.x;
    const int tx = t & 15, ty = t >> 4;
    const int nb = blockIdx.x, ob = blockIdx.y, b = blockIdx.z;
    const float* Wsel = ob ? Wk : Wq;
    const float* xb = x + (size_t)b * C_ * (size_t)NSP + (size_t)nb * 128;

    float acc[8][8];
#pragma unroll
    for (int i = 0; i < 8; i++)
#pragma unroll
        for (int j = 0; j < 8; j++) acc[i][j] = 0.f;

    for (int c0 = 0; c0 < 256; c0 += 16) {
        // stage X tile [16 c][128 n]
#pragma unroll
        for (int i = 0; i < 2; i++) {
            int idx = t + i * 256;
            int r = idx >> 5, col = (idx & 31) << 2;
            *(float4*)&Xs[r][col] =
                *(const float4*)(xb + (size_t)(c0 + r) * NSP + col);
        }
        // stage W tile transposed: Ws[kc][o]
#pragma unroll
        for (int i = 0; i < 2; i++) {
            int idx = t + i * 256;
            int o = idx >> 2, c4 = (idx & 3) << 2;
            float4 w = *(const float4*)(Wsel + o * 256 + c0 + c4);
            Ws[c4 + 0][o] = w.x; Ws[c4 + 1][o] = w.y;
            Ws[c4 + 2][o] = w.z; Ws[c4 + 3][o] = w.w;
        }
        __syncthreads();
#pragma unroll
        for (int kc = 0; kc < 16; kc++) {
            float4 x0 = *(const float4*)&Xs[kc][tx * 8];
            float4 x1 = *(const float4*)&Xs[kc][tx * 8 + 4];
            float4 w0 = *(const float4*)&Ws[kc][ty * 8];
            float4 w1 = *(const float4*)&Ws[kc][ty * 8 + 4];
            float xr[8] = {x0.x, x0.y, x0.z, x0.w, x1.x, x1.y, x1.z, x1.w};
            float wr[8] = {w0.x, w0.y, w0.z, w0.w, w1.x, w1.y, w1.z, w1.w};
#pragma unroll
            for (int i = 0; i < 8; i++)
#pragma unroll
                for (int j = 0; j < 8; j++)
                    acc[i][j] += wr[i] * xr[j];
        }
        __syncthreads();
    }

    size_t obase = ((size_t)(b * 256 + ob * 128 + ty * 8)) * NSP
                 + (size_t)nb * 128 + tx * 8;
#pragma unroll
    for (int i = 0; i < 8; i++) {
        ushort_t u[8];
#pragma unroll
        for (int j = 0; j < 8; j++) u[j] = f2bf(acc[i][j]);
        uint4 pk;
        pk.x = (uint_t)u[0] | ((uint_t)u[1] << 16);
        pk.y = (uint_t)u[2] | ((uint_t)u[3] << 16);
        pk.z = (uint_t)u[4] | ((uint_t)u[5] << 16);
        pk.w = (uint_t)u[6] | ((uint_t)u[7] << 16);
        *(uint4*)(qk + obase + (size_t)i * NSP) = pk;
    }
}

// ---------------------------------------------------------------------------
// K2: depthwise 3x3x3 conv + bias -> v (bf16), v stored into d_out scratch.
//  grid (108, 512=b*256+c); block 256.  4 outputs along d per thread.
// ---------------------------------------------------------------------------
__global__ __launch_bounds__(256) void k2_conv(
    const float* __restrict__ x, const float* __restrict__ Wv,
    const float* __restrict__ bv, ushort_t* __restrict__ v)
{
    const int gy = blockIdx.y;
    const int b = gy >> 8, c = gy & 255;
    const int qid = blockIdx.x * 256 + threadIdx.x;  // < 27648
    const int dd0  = (qid % 12) * 4;
    const int rest = qid / 12;                        // hh*48+ww
    const int ww = rest % 48, hh = rest / 48;

    float wv[27];
    {
        const float* w = Wv + c * 27;
#pragma unroll
        for (int i = 0; i < 27; i++) wv[i] = w[i];
    }
    const float bias = bv[c];
    const float* xb = x + ((size_t)(b * 256 + c)) * NSP;

    float a0 = bias, a1 = bias, a2 = bias, a3 = bias;
#pragma unroll
    for (int dh = 0; dh < 3; dh++) {
        int ih = hh + dh - 1;
        if (ih < 0 || ih >= 48) continue;
#pragma unroll
        for (int dw = 0; dw < 3; dw++) {
            int iw = ww + dw - 1;
            if (iw < 0 || iw >= 48) continue;
            const float* row = xb + ((size_t)(ih * 48 + iw)) * 48;
            float4 m  = *(const float4*)(row + dd0);
            float  lm = (dd0 > 0)  ? row[dd0 - 1] : 0.f;
            float  rp = (dd0 < 44) ? row[dd0 + 4] : 0.f;
            const int wb = (dh * 3 + dw) * 3;
            float w0 = wv[wb], w1 = wv[wb + 1], w2 = wv[wb + 2];
            a0 += w0 * lm  + w1 * m.x + w2 * m.y;
            a1 += w0 * m.x + w1 * m.y + w2 * m.z;
            a2 += w0 * m.y + w1 * m.z + w2 * m.w;
            a3 += w0 * m.z + w1 * m.w + w2 * rp;
        }
    }
    ushort4 o;
    o.x = f2bf(a0); o.y = f2bf(a1); o.z = f2bf(a2); o.w = f2bf(a3);
    *(ushort4*)(v + (size_t)gy * NSP + (size_t)rest * 48 + dd0) = o;
}

// ---------------------------------------------------------------------------
// K3: KVu[bh][kq][cv] += sum_n exp(k[kq][n]) * v[cv][n]
//     SE[b*128+h*32+kq]  += sum_n exp(k[kq][n])   (fused, was k3b)
//  grid (108 pos-blocks of 1024, 8 = b*4+h); block 256 (4 waves).
//  LDS chunk = 256 positions; thread owns 4kq x 8cv accumulators.
// ---------------------------------------------------------------------------
__global__ __launch_bounds__(256) void k3_kv(
    const ushort_t* __restrict__ qk, const ushort_t* __restrict__ v,
    float* __restrict__ KVu, float* __restrict__ SE)
{
    __shared__ __align__(16) char smem[49920];
    __shared__ float se_l[32];
    ushort_t* ks = (ushort_t*)smem;                 // [32][260] bf16
    ushort_t* vs = (ushort_t*)(smem + 16640);       // [64][260] bf16
    const int S = 260;

    const int bh = blockIdx.y;
    const int b = bh >> 2, h = bh & 3;
    const int t = threadIdx.x;
    const int lane = t & 63, w = t >> 6;
    const int kq0 = (lane >> 3) * 4;
    const int cv0 = (lane & 7) * 8;

    if (t < 32) se_l[t] = 0.f;   // covered by the first __syncthreads below

    const ushort_t* kbase0 = qk + ((size_t)(b * 256 + 128 + h * 32)) * NSP;
    const ushort_t* vbase0 = v  + ((size_t)(b * 256 + h * 64)) * NSP;

    float acc[4][8];
#pragma unroll
    for (int r = 0; r < 4; r++)
#pragma unroll
        for (int u = 0; u < 8; u++) acc[r][u] = 0.f;
    float seSum[4] = {0.f, 0.f, 0.f, 0.f};

    for (int ch = 0; ch < 4; ch++) {
        const int pos = blockIdx.x * 1024 + ch * 256;
        // stage k (with exp) : 32 rows x 256, accumulate row-sums of exp
#pragma unroll
        for (int i = 0; i < 4; i++) {
            int g = t + i * 256;
            int r = g >> 5, seg = (g & 31) * 8;
            uint4 raw = *(const uint4*)(kbase0 + (size_t)r * NSP + pos + seg);
            const ushort_t* in = (const ushort_t*)&raw;
            union { ushort_t s[8]; uint2 d[2]; } tmp;
            float ls = 0.f;
#pragma unroll
            for (int e = 0; e < 8; e++) {
                float ev = __expf(bf2f(in[e]));
                ls += ev;
                tmp.s[e] = f2bf(ev);
            }
            seSum[i] += ls;
            ushort_t* dst = ks + r * S + seg;
            *(uint2*)dst       = tmp.d[0];
            *(uint2*)(dst + 4) = tmp.d[1];
        }
        // stage v : 64 rows x 256 (copy)
#pragma unroll
        for (int i = 0; i < 8; i++) {
            int g = t + i * 256;
            int r = g >> 5, seg = (g & 31) * 8;
            uint4 raw = *(const uint4*)(vbase0 + (size_t)r * NSP + pos + seg);
            ushort_t* dst = vs + r * S + seg;
            *(uint2*)dst       = make_uint2(raw.x, raw.y);
            *(uint2*)(dst + 4) = make_uint2(raw.z, raw.w);
        }
        __syncthreads();
        // compute: wave w covers positions [w*64, w*64+64)
#pragma unroll 4
        for (int i = 0; i < 16; i++) {
            int p = w * 64 + i * 4;
            float kf[4][4];
#pragma unroll
            for (int r = 0; r < 4; r++) {
                uint2 kr = *(const uint2*)(ks + (kq0 + r) * S + p);
                const ushort_t* u = (const ushort_t*)&kr;
                kf[r][0] = bf2f(u[0]); kf[r][1] = bf2f(u[1]);
                kf[r][2] = bf2f(u[2]); kf[r][3] = bf2f(u[3]);
            }
#pragma unroll
            for (int uu = 0; uu < 8; uu++) {
                uint2 vr = *(const uint2*)(vs + (cv0 + uu) * S + p);
                const ushort_t* u = (const ushort_t*)&vr;
                float vf0 = bf2f(u[0]), vf1 = bf2f(u[1]);
                float vf2 = bf2f(u[2]), vf3 = bf2f(u[3]);
#pragma unroll
                for (int r = 0; r < 4; r++) {
                    acc[r][uu] += kf[r][0] * vf0 + kf[r][1] * vf1
                                + kf[r][2] * vf2 + kf[r][3] * vf3;
                }
            }
        }
        __syncthreads();
    }

    // block reductions: KV across 4 waves (LDS), SE per-row (LDS atomics)
    float* red = (float*)smem;   // 4*2048 floats = 32KB (aliases ks/vs, done)
#pragma unroll
    for (int r = 0; r < 4; r++)
#pragma unroll
        for (int u = 0; u < 8; u++)
            red[w * 2048 + (kq0 + r) * 64 + cv0 + u] = acc[r][u];
#pragma unroll
    for (int i = 0; i < 4; i++)
        atomicAdd(&se_l[(t >> 5) + i * 8], seSum[i]);
    __syncthreads();
    float* KVb = KVu + (size_t)bh * 2048;
    for (int e = t; e < 2048; e += 256) {
        float s = red[e] + red[e + 2048] + red[e + 4096] + red[e + 6144];
        atomicAdd(KVb + e, s);
    }
    if (t < 32)
        atomicAdd(SE + b * 128 + h * 32 + t, se_l[t]);
}

// ---------------------------------------------------------------------------
// K4: out[b][h*64+cv][n] = sum_kq softmax_kq(q)[kq][n] * KVu[kq][cv]/SE[kq]
//                          / (1+EPS)
//  grid (432 chunks of 256 pos, 8 = b*4+h); block 256.
//  Phase B mapping: pcol=t&63 (position quad), crow=t>>6 (channel quarter)
//  -> 1KB fully-coalesced stores, wave-broadcast KV reads.
// ---------------------------------------------------------------------------
__global__ __launch_bounds__(256) void k4_fin(
    const ushort_t* __restrict__ qk, const float* __restrict__ KVu,
    const float* __restrict__ SE, float* __restrict__ out)
{
    __shared__ float qsf[32 * 260];
    __shared__ float KVs[2048];
    const int bh = blockIdx.y;
    const int b = bh >> 2, h = bh & 3;
    const int pos0 = blockIdx.x * 256;
    const int t = threadIdx.x;

    // KV with SE + (1+eps) folded in
    {
        const float* src = KVu + (size_t)bh * 2048;
        const float* se  = SE + b * 128 + h * 32;
        int kq = t >> 3;
        float inv = 1.0f / (se[kq] * (1.0f + EPS_));
        float4 a = *(const float4*)(src + t * 8);
        float4 c = *(const float4*)(src + t * 8 + 4);
        a.x *= inv; a.y *= inv; a.z *= inv; a.w *= inv;
        c.x *= inv; c.y *= inv; c.z *= inv; c.w *= inv;
        *(float4*)(KVs + t * 8)     = a;
        *(float4*)(KVs + t * 8 + 4) = c;
    }
    // phase A: per-position q softmax over 32 features
    {
        const int p = pos0 + t;
        const ushort_t* qb = qk + ((size_t)(b * 256 + h * 32)) * NSP + p;
        float e[32];
        float s = 0.f;
#pragma unroll
        for (int r = 0; r < 32; r++) {
            e[r] = __expf(bf2f(qb[(size_t)r * NSP]));
            s += e[r];
        }
        float inv = 1.0f / s;
#pragma unroll
        for (int r = 0; r < 32; r++) qsf[r * 260 + t] = e[r] * inv;
    }
    __syncthreads();

    // phase B: out tile [64 cv][256 pos]; thread = 16 ch x 4 pos
    const int pcol = t & 63;
    const int crow = t >> 6;
    float acc[16][4];
#pragma unroll
    for (int u = 0; u < 16; u++)
#pragma unroll
        for (int e = 0; e < 4; e++) acc[u][e] = 0.f;

#pragma unroll 4
    for (int kq = 0; kq < 32; kq++) {
        float4 qv = *(const float4*)&qsf[kq * 260 + pcol * 4];
        const float* kv = KVs + kq * 64 + crow * 16;
        float4 k0 = *(const float4*)(kv);
        float4 k1 = *(const float4*)(kv + 4);
        float4 k2 = *(const float4*)(kv + 8);
        float4 k3 = *(const float4*)(kv + 12);
        float kk[16] = {k0.x, k0.y, k0.z, k0.w, k1.x, k1.y, k1.z, k1.w,
                        k2.x, k2.y, k2.z, k2.w, k3.x, k3.y, k3.z, k3.w};
#pragma unroll
        for (int u = 0; u < 16; u++) {
            acc[u][0] += kk[u] * qv.x;
            acc[u][1] += kk[u] * qv.y;
            acc[u][2] += kk[u] * qv.z;
            acc[u][3] += kk[u] * qv.w;
        }
    }
    float* ob = out + ((size_t)(b * 256 + h * 64 + crow * 16)) * NSP
              + pos0 + pcol * 4;
#pragma unroll
    for (int u = 0; u < 16; u++) {
        *(float4*)(ob + (size_t)u * NSP) =
            make_float4(acc[u][0], acc[u][1], acc[u][2], acc[u][3]);
    }
}

// ---------------------------------------------------------------------------
extern "C" void kernel_launch(void* const* d_in, const int* in_sizes, int n_in,
                              void* d_out, int out_size, void* d_ws,
                              size_t ws_size, hipStream_t stream)
{
    const float* x  = (const float*)d_in[0];
    const float* Wq = (const float*)d_in[1];
    const float* Wk = (const float*)d_in[2];
    const float* Wv = (const float*)d_in[3];
    const float* bv = (const float*)d_in[4];
    float* out = (float*)d_out;

    // ws layout: qk bf16 [2][256][NSP] (113,246,208 B) | KVu f32 (65,536 B) | SE f32 (1,024 B)
    ushort_t* qk  = (ushort_t*)d_ws;
    float*    KVu = (float*)((char*)d_ws + 113246208);
    float*    SE  = (float*)((char*)d_ws + 113246208 + 65536);
    // v (bf16) scratch lives in the first half of d_out; K4 overwrites later.
    ushort_t* v = (ushort_t*)d_out;

    hipMemsetAsync(KVu, 0, 65536 + 1024, stream);

    k1_gemm<<<dim3(864, 2, 2), 256, 0, stream>>>(x, Wq, Wk, qk);
    k2_conv<<<dim3(108, 512), 256, 0, stream>>>(x, Wv, bv, v);
    k3_kv  <<<dim3(108, 8),   256, 0, stream>>>(qk, v, KVu, SE);
    k4_fin <<<dim3(432, 8),   256, 0, stream>>>(qk, KVu, SE, out);
}